// Round 9
// baseline (174.223 us; speedup 1.0000x reference)
//
#include <hip/hip_runtime.h>

#define HID 128
#define BM 64
#define BK 32
#define NBLK 64          // partition chunks (blocks in part_hist/part_scatter)
#define PTHREADS 1024    // threads per partition block
#define MAXBUCK 2048     // buckets of 32 dst nodes; supports n <= 65536

typedef unsigned short ushort_t;
typedef unsigned int uint_t;

__device__ __forceinline__ float bflo(uint_t u) { return __uint_as_float(u << 16); }
__device__ __forceinline__ float bfhi(uint_t u) { return __uint_as_float(u & 0xFFFF0000u); }
__device__ __forceinline__ uint_t f2bf(float f) {
    uint_t x = __float_as_uint(f);
    return (x + 0x7FFFu + ((x >> 16) & 1u)) >> 16;   // RNE
}

// ---------------------------------------------------------------------------
// Detect whether edge_index was materialized as int64 (odd 32-bit words all 0)
// or int32. Values are node ids in [0, 50000) so the high word of int64 is 0.
// ---------------------------------------------------------------------------
__global__ void detect_idx64(const int* __restrict__ E, int* __restrict__ flag) {
    int l = threadIdx.x;                       // 64 threads
    int v = E[2 * l + 1] | E[2 * (l + 64) + 1];
    unsigned long long b = __ballot(v != 0);
    if (l == 0) flag[0] = (b == 0ull) ? 1 : 0;
}

__device__ __forceinline__ int load_idx(const int* __restrict__ E, int pos, bool is64) {
    return is64 ? E[2 * pos] : E[pos];
}

// ---------------------------------------------------------------------------
// Register-blocked SGEMM: T = relu(X @ W + B)  (X: n x 128, W: 128 x 128)
// Block: 256 threads, tile BM=64 rows, BK=32 k-slice. Micro-tile 4 rows x
// 8 cols per thread; the 8 cols are split {tn*4..+3, 64+tn*4..+3} so LDS
// reads are 16B-stride => only 2-way bank aliasing (free on CDNA4).
// Next k-slice is prefetched into registers during the k-loop (issue-early /
// write-late) to hide HBM latency under compute.
// mode 0: write full T rows as bf16.  mode 1: fuse dot with Wf, write S only.
// ---------------------------------------------------------------------------
__global__ __launch_bounds__(256, 3) void mlp_gemm(
    const float* __restrict__ X, const float* __restrict__ W,
    const float* __restrict__ Bv, const float* __restrict__ Wf,
    ushort_t* __restrict__ T, float* __restrict__ S, int n, int mode)
{
    __shared__ float Xs[BK][BM + 1];     // transposed X tile, +1 pad  (8.3 KB)
    __shared__ float Wsh[BK][HID];       // W k-slice, natural layout (16 KB)

    const int t  = threadIdx.x;
    const int tn = t & 15;               // column-group 0..15
    const int tm = t >> 4;               // row-group 0..15 (4 rows each)
    const int base = blockIdx.x * BM;

    float acc[4][8];
#pragma unroll
    for (int r = 0; r < 4; ++r)
#pragma unroll
        for (int c = 0; c < 8; ++c) acc[r][c] = 0.f;

    float4 xv[2], wv[4];

    // ---- prefetch kb = 0 ----
#pragma unroll
    for (int p = 0; p < 2; ++p) {
        const int idx = p * 256 + t;
        const int row = idx >> 3;            // 0..63
        const int c4  = (idx & 7) * 4;       // 0..28
        const int gr  = base + row;
        xv[p] = (gr < n) ? *(const float4*)(X + (size_t)gr * HID + c4)
                         : float4{0.f, 0.f, 0.f, 0.f};
    }
#pragma unroll
    for (int p = 0; p < 4; ++p) {
        const int idx = p * 256 + t;
        const int kr  = idx >> 5;            // 0..31
        const int c4  = (idx & 31) * 4;      // 0..124
        wv[p] = *(const float4*)(W + (size_t)kr * HID + c4);
    }

    for (int kb = 0; kb < HID; kb += BK) {
        __syncthreads();                     // previous LDS consumers done
        // ---- write staged regs -> LDS ----
#pragma unroll
        for (int p = 0; p < 2; ++p) {
            const int idx = p * 256 + t;
            const int row = idx >> 3;
            const int c4  = (idx & 7) * 4;
            Xs[c4 + 0][row] = xv[p].x;
            Xs[c4 + 1][row] = xv[p].y;
            Xs[c4 + 2][row] = xv[p].z;
            Xs[c4 + 3][row] = xv[p].w;
        }
#pragma unroll
        for (int p = 0; p < 4; ++p) {
            const int idx = p * 256 + t;
            const int kr  = idx >> 5;
            const int c4  = (idx & 31) * 4;
            *(float4*)(&Wsh[kr][c4]) = wv[p];
        }
        __syncthreads();

        // ---- issue prefetch for kb+BK (overlaps with k-loop below) ----
        if (kb + BK < HID) {
            const int kn = kb + BK;
#pragma unroll
            for (int p = 0; p < 2; ++p) {
                const int idx = p * 256 + t;
                const int row = idx >> 3;
                const int c4  = (idx & 7) * 4;
                const int gr  = base + row;
                xv[p] = (gr < n) ? *(const float4*)(X + (size_t)gr * HID + kn + c4)
                                 : float4{0.f, 0.f, 0.f, 0.f};
            }
#pragma unroll
            for (int p = 0; p < 4; ++p) {
                const int idx = p * 256 + t;
                const int kr  = idx >> 5;
                const int c4  = (idx & 31) * 4;
                wv[p] = *(const float4*)(W + (size_t)(kn + kr) * HID + c4);
            }
        }

        // ---- compute ----
#pragma unroll
        for (int k = 0; k < BK; ++k) {
            float xr[4], wc[8];
            *(float4*)&xr[0] = *(const float4*)&Xs[k][tm * 4];
            *(float4*)&wc[0] = *(const float4*)&Wsh[k][tn * 4];
            *(float4*)&wc[4] = *(const float4*)&Wsh[k][64 + tn * 4];
#pragma unroll
            for (int r = 0; r < 4; ++r)
#pragma unroll
                for (int c = 0; c < 8; ++c)
                    acc[r][c] = fmaf(xr[r], wc[c], acc[r][c]);
        }
    }

    // epilogue: bias + relu on the split columns {tn*4, 64+tn*4}
    float bv[8];
    *(float4*)&bv[0] = *(const float4*)(Bv + tn * 4);
    *(float4*)&bv[4] = *(const float4*)(Bv + 64 + tn * 4);

    if (mode == 0) {
#pragma unroll
        for (int r = 0; r < 4; ++r) {
            const int gr = base + tm * 4 + r;
            if (gr >= n) break;
            float o[8];
#pragma unroll
            for (int c = 0; c < 8; ++c) o[c] = fmaxf(acc[r][c] + bv[c], 0.f);
            uint2 w0, w1;
            w0.x = f2bf(o[0]) | (f2bf(o[1]) << 16);
            w0.y = f2bf(o[2]) | (f2bf(o[3]) << 16);
            w1.x = f2bf(o[4]) | (f2bf(o[5]) << 16);
            w1.y = f2bf(o[6]) | (f2bf(o[7]) << 16);
            *(uint2*)(T + (size_t)gr * HID + tn * 4)      = w0;
            *(uint2*)(T + (size_t)gr * HID + 64 + tn * 4) = w1;
        }
    } else {
        float wf[8];
        *(float4*)&wf[0] = *(const float4*)(Wf + tn * 4);
        *(float4*)&wf[4] = *(const float4*)(Wf + 64 + tn * 4);
        float p[4];
#pragma unroll
        for (int r = 0; r < 4; ++r) {
            float s = 0.f;
#pragma unroll
            for (int c = 0; c < 8; ++c)
                s += fmaxf(acc[r][c] + bv[c], 0.f) * wf[c];
            p[r] = s;
        }
#pragma unroll
        for (int m = 1; m <= 8; m <<= 1)
#pragma unroll
            for (int r = 0; r < 4; ++r) p[r] += __shfl_xor(p[r], m);
        if (tn == 0) {
#pragma unroll
            for (int r = 0; r < 4; ++r) {
                const int gr = base + tm * 4 + r;
                if (gr < n) S[gr] = p[r];
            }
        }
    }
}

// ---------------------------------------------------------------------------
// Partition stage 1: per-block LDS histogram of dst buckets (32 dsts/bucket).
// No global atomics. histT layout: [bucket][blk] for linear scan.
// ---------------------------------------------------------------------------
__global__ __launch_bounds__(PTHREADS) void part_hist(
    const int* __restrict__ E, const int* __restrict__ flag,
    int* __restrict__ histT, int n_edges, int n_nodes, int nbuck)
{
    __shared__ int h[MAXBUCK];
    for (int i = threadIdx.x; i < nbuck; i += PTHREADS) h[i] = 0;
    __syncthreads();
    const bool is64 = (flag[0] != 0);
    const int chunk = (n_edges + NBLK - 1) / NBLK;
    const int c0 = blockIdx.x * chunk;
    const int c1 = min(c0 + chunk, n_edges);
    for (int e = c0 + (int)threadIdx.x; e < c1; e += PTHREADS) {
        const int dst = load_idx(E, n_edges + e, is64);
        if ((unsigned)dst < (unsigned)n_nodes) atomicAdd(&h[dst >> 5], 1);
    }
    __syncthreads();
    for (int i = threadIdx.x; i < nbuck; i += PTHREADS)
        histT[i * NBLK + blockIdx.x] = h[i];
}

// ---------------------------------------------------------------------------
// Generic hierarchical exclusive scan (3 kernels) over m elements.
// ---------------------------------------------------------------------------
__global__ __launch_bounds__(256) void scang_blk(
    const int* __restrict__ A, int* __restrict__ out,
    int* __restrict__ bsum, int m)
{
    __shared__ int sd[256];
    const int t = threadIdx.x;
    const int i = blockIdx.x * 256 + t;
    const int v = (i < m) ? A[i] : 0;
    sd[t] = v;
    __syncthreads();
    for (int d = 1; d < 256; d <<= 1) {
        const int u = (t >= d) ? sd[t - d] : 0;
        __syncthreads();
        sd[t] += u;
        __syncthreads();
    }
    if (i < m) out[i] = sd[t] - v;           // local exclusive
    if (t == 255) bsum[blockIdx.x] = sd[255];
}

__global__ __launch_bounds__(256) void scang_top(
    int* __restrict__ bsum, int* __restrict__ totalSlot, int nb)
{
    __shared__ int sd[256];
    const int t = threadIdx.x;
    const int chunk = (nb + 255) / 256;
    const int lo = t * chunk;
    const int hi = min(lo + chunk, nb);
    int s = 0;
    for (int i = lo; i < hi; ++i) s += bsum[i];
    sd[t] = s;
    __syncthreads();
    for (int d = 1; d < 256; d <<= 1) {
        const int u = (t >= d) ? sd[t - d] : 0;
        __syncthreads();
        sd[t] += u;
        __syncthreads();
    }
    int run = sd[t] - s;
    for (int i = lo; i < hi; ++i) {
        const int c = bsum[i];
        bsum[i] = run;                        // block base
        run += c;
    }
    if (t == 255) totalSlot[0] = sd[255];
}

__global__ __launch_bounds__(256) void scang_add(
    int* __restrict__ out, const int* __restrict__ bsum, int m)
{
    const int i = blockIdx.x * 256 + threadIdx.x;
    if (i < m) out[i] += bsum[blockIdx.x];
}

// ---------------------------------------------------------------------------
// Partition stage 2: scatter packed (src | dlow<<16) into per-(block,bucket)
// EXCLUSIVE ranges. Positions from LDS counters -> no global atomics; each
// output region is written by exactly one block -> L2 write-combining works.
// ---------------------------------------------------------------------------
__global__ __launch_bounds__(PTHREADS) void part_scatter(
    const int* __restrict__ E, const int* __restrict__ flag,
    const int* __restrict__ base, uint_t* __restrict__ pe,
    int n_edges, int n_nodes, int nbuck)
{
    __shared__ int cur[MAXBUCK];
    for (int i = threadIdx.x; i < nbuck; i += PTHREADS)
        cur[i] = base[i * NBLK + blockIdx.x];
    __syncthreads();
    const bool is64 = (flag[0] != 0);
    const int chunk = (n_edges + NBLK - 1) / NBLK;
    const int c0 = blockIdx.x * chunk;
    const int c1 = min(c0 + chunk, n_edges);
    for (int e = c0 + (int)threadIdx.x; e < c1; e += PTHREADS) {
        const int src = load_idx(E, e, is64);
        const int dst = load_idx(E, n_edges + e, is64);
        if ((unsigned)src >= (unsigned)n_nodes || (unsigned)dst >= (unsigned)n_nodes) continue;
        const int p = atomicAdd(&cur[dst >> 5], 1);
        pe[p] = (uint_t)src | ((uint_t)(dst & 31) << 16);
    }
}

// ---------------------------------------------------------------------------
// Per-bucket exact CSR: one wave per bucket of 32 dsts. Count per dst,
// shfl-scan, write offs[dst] and place src into block-exclusive region.
// ---------------------------------------------------------------------------
__global__ __launch_bounds__(64) void bucket_csr(
    const uint_t* __restrict__ pe, const int* __restrict__ base,
    int* __restrict__ offs, int* __restrict__ srcS,
    int n_nodes, int nbuck)
{
    __shared__ int cnt[32];
    __shared__ int cur[32];
    const int b = blockIdx.x;
    const int l = threadIdx.x;
    const int start = base[b * NBLK];
    const int end   = base[(b + 1) * NBLK];   // base has nbuck*NBLK+1 entries
    if (l < 32) cnt[l] = 0;
    __syncthreads();
    for (int i = start + l; i < end; i += 64)
        atomicAdd(&cnt[(pe[i] >> 16) & 31], 1);
    __syncthreads();
    if (l < 32) {
        const int v = cnt[l];
        int s = v;
        for (int d = 1; d < 32; d <<= 1) {
            const int u = __shfl_up(s, d, 64);
            if (l >= d) s += u;
        }
        const int o = start + s - v;          // exclusive within bucket
        const int dst = b * 32 + l;
        if (dst < n_nodes) offs[dst] = o;
        cur[l] = o;
    }
    __syncthreads();
    for (int i = start + l; i < end; i += 64) {
        const uint_t w = pe[i];
        const int p = atomicAdd(&cur[(w >> 16) & 31], 1);
        srcS[p] = (int)(w & 0xFFFFu);
    }
    if (b == 0 && l == 0) offs[n_nodes] = base[nbuck * NBLK];
}

// ---------------------------------------------------------------------------
// Gather-reduce (layer 1): H[node] = sum over edges(dst==node) of T[src].
// One 32-lane group per node, lane owns 4 features (bf16 in T, fp32 acc).
// Unrolled by 2: two independent load->add chains in flight.
// ---------------------------------------------------------------------------
__global__ __launch_bounds__(256) void gather_vec(
    const ushort_t* __restrict__ T, const int* __restrict__ offs,
    const int* __restrict__ srcSorted, float* __restrict__ H, int n_nodes)
{
    const int l32  = threadIdx.x & 31;
    const int j0   = l32 * 4;
    const int grp  = (int)((blockIdx.x * blockDim.x + threadIdx.x) >> 5);
    const int ngrp = (int)((gridDim.x * blockDim.x) >> 5);
    for (int node = grp; node < n_nodes; node += ngrp) {
        const int k0 = offs[node];
        const int k1 = offs[node + 1];
        float4 a0 = {0.f, 0.f, 0.f, 0.f};
        float4 a1 = {0.f, 0.f, 0.f, 0.f};
        int k = k0;
        for (; k + 1 < k1; k += 2) {
            const int s0 = srcSorted[k];
            const int s1 = srcSorted[k + 1];
            const uint2 u0 = *(const uint2*)(T + (size_t)s0 * HID + j0);
            const uint2 u1 = *(const uint2*)(T + (size_t)s1 * HID + j0);
            a0.x += bflo(u0.x); a0.y += bfhi(u0.x);
            a0.z += bflo(u0.y); a0.w += bfhi(u0.y);
            a1.x += bflo(u1.x); a1.y += bfhi(u1.x);
            a1.z += bflo(u1.y); a1.w += bfhi(u1.y);
        }
        if (k < k1) {
            const int s0 = srcSorted[k];
            const uint2 u0 = *(const uint2*)(T + (size_t)s0 * HID + j0);
            a0.x += bflo(u0.x); a0.y += bfhi(u0.x);
            a0.z += bflo(u0.y); a0.w += bfhi(u0.y);
        }
        a0.x += a1.x; a0.y += a1.y; a0.z += a1.z; a0.w += a1.w;
        *(float4*)(H + (size_t)node * HID + j0) = a0;
    }
}

// ---------------------------------------------------------------------------
// Gather-reduce (readout): O[node] = bf + sum over edges(dst==node) of S[src].
// ---------------------------------------------------------------------------
__global__ __launch_bounds__(256) void gather_scalar(
    const float* __restrict__ S, const int* __restrict__ offs,
    const int* __restrict__ srcSorted, const float* __restrict__ bf,
    float* __restrict__ O, int n_nodes)
{
    const int t  = blockIdx.x * blockDim.x + threadIdx.x;
    const int nt = gridDim.x * blockDim.x;
    for (int node = t; node < n_nodes; node += nt) {
        const int k0 = offs[node];
        const int k1 = offs[node + 1];
        float acc = bf[0];
        for (int k = k0; k < k1; ++k) acc += S[srcSorted[k]];
        O[node] = acc;
    }
}

// ---------------------------------------------------------------------------
// Fallback atomic path (used only if workspace is too small for CSR)
// ---------------------------------------------------------------------------
__global__ __launch_bounds__(256) void scatter_vec(
    const ushort_t* __restrict__ T, const int* __restrict__ E,
    const int* __restrict__ flag, float* __restrict__ H,
    int n_edges, int n_nodes)
{
    const bool is64 = (flag[0] != 0);
    const int l32 = threadIdx.x & 31;
    const int j0  = l32 * 4;
    const int grp  = (int)((blockIdx.x * blockDim.x + threadIdx.x) >> 5);
    const int ngrp = (int)((gridDim.x * blockDim.x) >> 5);
    for (int e = grp; e < n_edges; e += ngrp) {
        const int src = load_idx(E, e, is64);
        const int dst = load_idx(E, n_edges + e, is64);
        if ((unsigned)src >= (unsigned)n_nodes || (unsigned)dst >= (unsigned)n_nodes) continue;
        const uint2 u = *(const uint2*)(T + (size_t)src * HID + j0);
        float* hp = H + (size_t)dst * HID + j0;
        unsafeAtomicAdd(hp + 0, bflo(u.x));
        unsafeAtomicAdd(hp + 1, bfhi(u.x));
        unsafeAtomicAdd(hp + 2, bflo(u.y));
        unsafeAtomicAdd(hp + 3, bfhi(u.y));
    }
}

__global__ __launch_bounds__(256) void scatter_scalar(
    const float* __restrict__ S, const int* __restrict__ E,
    const int* __restrict__ flag, float* __restrict__ O,
    int n_edges, int n_nodes)
{
    const bool is64 = (flag[0] != 0);
    const int t  = blockIdx.x * blockDim.x + threadIdx.x;
    const int nt = gridDim.x * blockDim.x;
    for (int e = t; e < n_edges; e += nt) {
        const int src = load_idx(E, e, is64);
        const int dst = load_idx(E, n_edges + e, is64);
        if ((unsigned)src >= (unsigned)n_nodes || (unsigned)dst >= (unsigned)n_nodes) continue;
        unsafeAtomicAdd(O + dst, S[src]);
    }
}

__global__ void init_out(float* __restrict__ O, const float* __restrict__ bf, int n) {
    int i = blockIdx.x * blockDim.x + threadIdx.x;
    if (i < n) O[i] = bf[0];
}

extern "C" void kernel_launch(void* const* d_in, const int* in_sizes, int n_in,
                              void* d_out, int out_size, void* d_ws, size_t ws_size,
                              hipStream_t stream) {
    const float* x  = (const float*)d_in[0];
    const int*   E  = (const int*)d_in[1];
    const float* W1 = (const float*)d_in[2];
    const float* b1 = (const float*)d_in[3];
    const float* W2 = (const float*)d_in[4];
    const float* b2 = (const float*)d_in[5];
    const float* Wf = (const float*)d_in[6];
    const float* bf = (const float*)d_in[7];
    float* out = (float*)d_out;

    const int n  = in_sizes[0] / HID;   // 50000 nodes
    const int ne = in_sizes[1] / 2;     // 800000 edges
    const int nbuck  = (n + 31) / 32;   // 1563 buckets
    const int m      = nbuck * NBLK;    // 100k partition counters
    const int nbscan = (m + 255) / 256; // scan blocks

    const size_t featB = (size_t)n * HID * 4;
    char* ws = (char*)d_ws;
    int*   flag = (int*)ws;
    ushort_t* t1 = (ushort_t*)(ws + 1024);             // n*128 bf16 (in featB slot)
    float* h1   = (float*)(ws + 1024 + featB);
    char*  p    = ws + 1024 + 2 * featB;
    uint_t* pe       = (uint_t*)p;              p += (size_t)ne * 4;
    int*   srcSorted = (int*)p;                 p += (size_t)ne * 4;
    int*   offs      = (int*)p;                 p += (size_t)(n + 1) * 4;
    int*   histT     = (int*)p;                 p += (size_t)m * 4;
    int*   basea     = (int*)p;                 p += (size_t)(m + 1) * 4;
    int*   bsum      = (int*)p;                 p += (size_t)nbscan * 4;
    const size_t needed = (size_t)(p - ws);
    float* s = (float*)(ws + 1024);   // t1 dead after aggregation; reuse slot

    const int gemm_grid = (n + BM - 1) / BM;

    detect_idx64<<<1, 64, 0, stream>>>(E, flag);

    // layer 1 per-node transform (bf16 out)
    mlp_gemm<<<gemm_grid, 256, 0, stream>>>(x, W1, b1, nullptr, t1, nullptr, n, 0);

    if (ws_size >= needed && n <= 65536 && nbuck <= MAXBUCK) {
        // ---- coalesced counting partition + exact per-bucket CSR ----
        part_hist<<<NBLK, PTHREADS, 0, stream>>>(E, flag, histT, ne, n, nbuck);
        scang_blk<<<nbscan, 256, 0, stream>>>(histT, basea, bsum, m);
        scang_top<<<1, 256, 0, stream>>>(bsum, basea + m, nbscan);
        scang_add<<<nbscan, 256, 0, stream>>>(basea, bsum, m);
        part_scatter<<<NBLK, PTHREADS, 0, stream>>>(E, flag, basea, pe, ne, n, nbuck);
        bucket_csr<<<nbuck, 64, 0, stream>>>(pe, basea, offs, srcSorted, n, nbuck);

        // ---- aggregation without atomics ----
        gather_vec<<<2048, 256, 0, stream>>>(t1, offs, srcSorted, h1, n);

        // layer 2 fused with readout: s[m] = relu(h1[m]@W2+b2) . Wf
        mlp_gemm<<<gemm_grid, 256, 0, stream>>>(h1, W2, b2, Wf, nullptr, s, n, 1);

        gather_scalar<<<1024, 256, 0, stream>>>(s, offs, srcSorted, bf, out, n);
    } else {
        // ---- fallback: atomic scatter path ----
        (void)hipMemsetAsync(h1, 0, featB, stream);
        scatter_vec<<<8192, 256, 0, stream>>>(t1, E, flag, h1, ne, n);
        mlp_gemm<<<gemm_grid, 256, 0, stream>>>(h1, W2, b2, Wf, nullptr, s, n, 1);
        init_out<<<(n + 255) / 256, 256, 0, stream>>>(out, bf, n);
        scatter_scalar<<<2048, 256, 0, stream>>>(s, E, flag, out, ne, n);
    }
}

// Round 10
// 119.797 us; speedup vs baseline: 1.4543x; 1.4543x over previous
//
#include <hip/hip_runtime.h>

#define HID 128
#define NBLK 64          // partition chunks (blocks in part_hist/part_scatter)
#define PTHREADS 1024    // threads per partition block
#define MAXBUCK 2048     // buckets of 32 dst nodes; supports n <= 65536

typedef unsigned short ushort_t;
typedef unsigned int uint_t;
typedef short bf16x8 __attribute__((ext_vector_type(8)));
typedef float f32x4 __attribute__((ext_vector_type(4)));

__device__ __forceinline__ float bflo(uint_t u) { return __uint_as_float(u << 16); }
__device__ __forceinline__ float bfhi(uint_t u) { return __uint_as_float(u & 0xFFFF0000u); }
__device__ __forceinline__ uint_t f2bf(float f) {
    uint_t x = __float_as_uint(f);
    return (x + 0x7FFFu + ((x >> 16) & 1u)) >> 16;   // RNE
}

// ---------------------------------------------------------------------------
// Detect whether edge_index was materialized as int64 (odd 32-bit words all 0)
// or int32. Values are node ids in [0, 50000) so the high word of int64 is 0.
// ---------------------------------------------------------------------------
__global__ void detect_idx64(const int* __restrict__ E, int* __restrict__ flag) {
    int l = threadIdx.x;                       // 64 threads
    int v = E[2 * l + 1] | E[2 * (l + 64) + 1];
    unsigned long long b = __ballot(v != 0);
    if (l == 0) flag[0] = (b == 0ull) ? 1 : 0;
}

__device__ __forceinline__ int load_idx(const int* __restrict__ E, int pos, bool is64) {
    return is64 ? E[2 * pos] : E[pos];
}

// ---------------------------------------------------------------------------
// One-time weight prep: Wt[col][k] = bf16(W[k][col]) for W1 and W2.
// 2 x 128x128 elems; grid 128 x 256 threads.
// ---------------------------------------------------------------------------
__global__ __launch_bounds__(256) void prep_w(
    const float* __restrict__ W1, const float* __restrict__ W2,
    ushort_t* __restrict__ wt1, ushort_t* __restrict__ wt2)
{
    const int id = blockIdx.x * 256 + threadIdx.x;       // 0..32767
    const float* W = (id < 16384) ? W1 : W2;
    ushort_t* O    = (id < 16384) ? wt1 : wt2;
    const int i   = id & 16383;
    const int col = i >> 7;
    const int k   = i & 127;
    O[col * 128 + k] = (ushort_t)f2bf(W[k * 128 + col]);
}

// ---------------------------------------------------------------------------
// MFMA GEMM: T = relu(X @ W + B) using v_mfma_f32_16x16x32_bf16.
// Block = 256 thr = 4 waves; each wave owns 16 rows x 128 cols.
// Wt (transposed bf16 W) staged once into LDS with granule-XOR swizzle
// (16B granule index g ^= col&7) so B-fragment ds_read_b128 is conflict-free.
// No per-K barriers: LDS is read-only after the single stage barrier.
// A fragment: lane l holds X[row=base+(l&15)][k=kk*32+(l>>4)*8 + j], j=0..7.
// B fragment: lane l holds W[k=kk*32+(l>>4)*8+j][col=ct*16+(l&15)].
// C/D layout (verified): col=lane&15, row=(lane>>4)*4+reg.
// mode 0: write T rows (bf16). mode 1: fuse dot with Wf, write scalar S.
// ---------------------------------------------------------------------------
__global__ __launch_bounds__(256) void mlp_mfma(
    const float* __restrict__ X, const ushort_t* __restrict__ Wt,
    const float* __restrict__ Bv, const float* __restrict__ Wf,
    ushort_t* __restrict__ T, float* __restrict__ S, int n, int mode)
{
    __shared__ ushort_t Wl[HID * HID];   // 32 KB, swizzled

    // stage Wt -> LDS (swizzled granules of 8 bf16 = 16B)
    {
        const uint4* src = (const uint4*)Wt;
        for (int o = threadIdx.x; o < 2048; o += 256) {
            const uint4 v = src[o];
            const int col = o >> 4;
            const int g   = o & 15;
            const int gs  = g ^ (col & 7);
            *(uint4*)(Wl + col * HID + gs * 8) = v;
        }
    }
    __syncthreads();

    const int l  = threadIdx.x & 63;
    const int wv = threadIdx.x >> 6;
    const int rowbase = blockIdx.x * 64 + wv * 16;
    const int lr = l & 15;               // A-row / B-col / C-col lane index
    const int lg = l >> 4;               // k-group / C-row group

    f32x4 acc[8];
#pragma unroll
    for (int ct = 0; ct < 8; ++ct) acc[ct] = (f32x4){0.f, 0.f, 0.f, 0.f};

    const int arow = rowbase + lr;
    const bool rok = (arow < n);

    for (int kk = 0; kk < 4; ++kk) {
        bf16x8 a;
        if (rok) {
            const float* xp = X + (size_t)arow * HID + kk * 32 + lg * 8;
            const float4 x0 = *(const float4*)xp;
            const float4 x1 = *(const float4*)(xp + 4);
            a[0] = (short)f2bf(x0.x); a[1] = (short)f2bf(x0.y);
            a[2] = (short)f2bf(x0.z); a[3] = (short)f2bf(x0.w);
            a[4] = (short)f2bf(x1.x); a[5] = (short)f2bf(x1.y);
            a[6] = (short)f2bf(x1.z); a[7] = (short)f2bf(x1.w);
        } else {
            a = (bf16x8){0, 0, 0, 0, 0, 0, 0, 0};
        }
#pragma unroll
        for (int ct = 0; ct < 8; ++ct) {
            const int col = ct * 16 + lr;
            const int g   = kk * 4 + lg;
            const int gs  = g ^ (col & 7);
            const bf16x8 b = *(const bf16x8*)(Wl + col * HID + gs * 8);
            acc[ct] = __builtin_amdgcn_mfma_f32_16x16x32_bf16(a, b, acc[ct], 0, 0, 0);
        }
    }

    if (mode == 0) {
#pragma unroll
        for (int ct = 0; ct < 8; ++ct) {
            const float bvc = Bv[ct * 16 + lr];
#pragma unroll
            for (int i = 0; i < 4; ++i) {
                const int r = rowbase + lg * 4 + i;
                if (r < n) {
                    const float v = fmaxf(acc[ct][i] + bvc, 0.f);
                    T[(size_t)r * HID + ct * 16 + lr] = (ushort_t)f2bf(v);
                }
            }
        }
    } else {
        float p0 = 0.f, p1 = 0.f, p2 = 0.f, p3 = 0.f;
#pragma unroll
        for (int ct = 0; ct < 8; ++ct) {
            const float bvc = Bv[ct * 16 + lr];
            const float wfc = Wf[ct * 16 + lr];
            p0 += fmaxf(acc[ct][0] + bvc, 0.f) * wfc;
            p1 += fmaxf(acc[ct][1] + bvc, 0.f) * wfc;
            p2 += fmaxf(acc[ct][2] + bvc, 0.f) * wfc;
            p3 += fmaxf(acc[ct][3] + bvc, 0.f) * wfc;
        }
#pragma unroll
        for (int m = 1; m <= 8; m <<= 1) {
            p0 += __shfl_xor(p0, m);
            p1 += __shfl_xor(p1, m);
            p2 += __shfl_xor(p2, m);
            p3 += __shfl_xor(p3, m);
        }
        if (lr == 0) {
            const int r = rowbase + lg * 4;
            if (r + 0 < n) S[r + 0] = p0;
            if (r + 1 < n) S[r + 1] = p1;
            if (r + 2 < n) S[r + 2] = p2;
            if (r + 3 < n) S[r + 3] = p3;
        }
    }
}

// ---------------------------------------------------------------------------
// Partition stage 1: per-block LDS histogram of dst buckets (32 dsts/bucket).
// ---------------------------------------------------------------------------
__global__ __launch_bounds__(PTHREADS) void part_hist(
    const int* __restrict__ E, const int* __restrict__ flag,
    int* __restrict__ histT, int n_edges, int n_nodes, int nbuck)
{
    __shared__ int h[MAXBUCK];
    for (int i = threadIdx.x; i < nbuck; i += PTHREADS) h[i] = 0;
    __syncthreads();
    const bool is64 = (flag[0] != 0);
    const int chunk = (n_edges + NBLK - 1) / NBLK;
    const int c0 = blockIdx.x * chunk;
    const int c1 = min(c0 + chunk, n_edges);
    for (int e = c0 + (int)threadIdx.x; e < c1; e += PTHREADS) {
        const int dst = load_idx(E, n_edges + e, is64);
        if ((unsigned)dst < (unsigned)n_nodes) atomicAdd(&h[dst >> 5], 1);
    }
    __syncthreads();
    for (int i = threadIdx.x; i < nbuck; i += PTHREADS)
        histT[i * NBLK + blockIdx.x] = h[i];
}

// ---------------------------------------------------------------------------
// Generic hierarchical exclusive scan (3 kernels) over m elements.
// ---------------------------------------------------------------------------
__global__ __launch_bounds__(256) void scang_blk(
    const int* __restrict__ A, int* __restrict__ out,
    int* __restrict__ bsum, int m)
{
    __shared__ int sd[256];
    const int t = threadIdx.x;
    const int i = blockIdx.x * 256 + t;
    const int v = (i < m) ? A[i] : 0;
    sd[t] = v;
    __syncthreads();
    for (int d = 1; d < 256; d <<= 1) {
        const int u = (t >= d) ? sd[t - d] : 0;
        __syncthreads();
        sd[t] += u;
        __syncthreads();
    }
    if (i < m) out[i] = sd[t] - v;           // local exclusive
    if (t == 255) bsum[blockIdx.x] = sd[255];
}

__global__ __launch_bounds__(256) void scang_top(
    int* __restrict__ bsum, int* __restrict__ totalSlot, int nb)
{
    __shared__ int sd[256];
    const int t = threadIdx.x;
    const int chunk = (nb + 255) / 256;
    const int lo = t * chunk;
    const int hi = min(lo + chunk, nb);
    int s = 0;
    for (int i = lo; i < hi; ++i) s += bsum[i];
    sd[t] = s;
    __syncthreads();
    for (int d = 1; d < 256; d <<= 1) {
        const int u = (t >= d) ? sd[t - d] : 0;
        __syncthreads();
        sd[t] += u;
        __syncthreads();
    }
    int run = sd[t] - s;
    for (int i = lo; i < hi; ++i) {
        const int c = bsum[i];
        bsum[i] = run;                        // block base
        run += c;
    }
    if (t == 255) totalSlot[0] = sd[255];
}

__global__ __launch_bounds__(256) void scang_add(
    int* __restrict__ out, const int* __restrict__ bsum, int m)
{
    const int i = blockIdx.x * 256 + threadIdx.x;
    if (i < m) out[i] += bsum[blockIdx.x];
}

// ---------------------------------------------------------------------------
// Partition stage 2: scatter packed (src | dlow<<16) into per-(block,bucket)
// EXCLUSIVE ranges.
// ---------------------------------------------------------------------------
__global__ __launch_bounds__(PTHREADS) void part_scatter(
    const int* __restrict__ E, const int* __restrict__ flag,
    const int* __restrict__ base, uint_t* __restrict__ pe,
    int n_edges, int n_nodes, int nbuck)
{
    __shared__ int cur[MAXBUCK];
    for (int i = threadIdx.x; i < nbuck; i += PTHREADS)
        cur[i] = base[i * NBLK + blockIdx.x];
    __syncthreads();
    const bool is64 = (flag[0] != 0);
    const int chunk = (n_edges + NBLK - 1) / NBLK;
    const int c0 = blockIdx.x * chunk;
    const int c1 = min(c0 + chunk, n_edges);
    for (int e = c0 + (int)threadIdx.x; e < c1; e += PTHREADS) {
        const int src = load_idx(E, e, is64);
        const int dst = load_idx(E, n_edges + e, is64);
        if ((unsigned)src >= (unsigned)n_nodes || (unsigned)dst >= (unsigned)n_nodes) continue;
        const int p = atomicAdd(&cur[dst >> 5], 1);
        pe[p] = (uint_t)src | ((uint_t)(dst & 31) << 16);
    }
}

// ---------------------------------------------------------------------------
// Per-bucket exact CSR: one wave per bucket of 32 dsts.
// ---------------------------------------------------------------------------
__global__ __launch_bounds__(64) void bucket_csr(
    const uint_t* __restrict__ pe, const int* __restrict__ base,
    int* __restrict__ offs, int* __restrict__ srcS,
    int n_nodes, int nbuck)
{
    __shared__ int cnt[32];
    __shared__ int cur[32];
    const int b = blockIdx.x;
    const int l = threadIdx.x;
    const int start = base[b * NBLK];
    const int end   = base[(b + 1) * NBLK];   // base has nbuck*NBLK+1 entries
    if (l < 32) cnt[l] = 0;
    __syncthreads();
    for (int i = start + l; i < end; i += 64)
        atomicAdd(&cnt[(pe[i] >> 16) & 31], 1);
    __syncthreads();
    if (l < 32) {
        const int v = cnt[l];
        int s = v;
        for (int d = 1; d < 32; d <<= 1) {
            const int u = __shfl_up(s, d, 64);
            if (l >= d) s += u;
        }
        const int o = start + s - v;          // exclusive within bucket
        const int dst = b * 32 + l;
        if (dst < n_nodes) offs[dst] = o;
        cur[l] = o;
    }
    __syncthreads();
    for (int i = start + l; i < end; i += 64) {
        const uint_t w = pe[i];
        const int p = atomicAdd(&cur[(w >> 16) & 31], 1);
        srcS[p] = (int)(w & 0xFFFFu);
    }
    if (b == 0 && l == 0) offs[n_nodes] = base[nbuck * NBLK];
}

// ---------------------------------------------------------------------------
// Gather-reduce (layer 1): H[node] = sum over edges(dst==node) of T[src].
// ---------------------------------------------------------------------------
__global__ __launch_bounds__(256) void gather_vec(
    const ushort_t* __restrict__ T, const int* __restrict__ offs,
    const int* __restrict__ srcSorted, float* __restrict__ H, int n_nodes)
{
    const int l32  = threadIdx.x & 31;
    const int j0   = l32 * 4;
    const int grp  = (int)((blockIdx.x * blockDim.x + threadIdx.x) >> 5);
    const int ngrp = (int)((gridDim.x * blockDim.x) >> 5);
    for (int node = grp; node < n_nodes; node += ngrp) {
        const int k0 = offs[node];
        const int k1 = offs[node + 1];
        float4 a0 = {0.f, 0.f, 0.f, 0.f};
        float4 a1 = {0.f, 0.f, 0.f, 0.f};
        int k = k0;
        for (; k + 1 < k1; k += 2) {
            const int s0 = srcSorted[k];
            const int s1 = srcSorted[k + 1];
            const uint2 u0 = *(const uint2*)(T + (size_t)s0 * HID + j0);
            const uint2 u1 = *(const uint2*)(T + (size_t)s1 * HID + j0);
            a0.x += bflo(u0.x); a0.y += bfhi(u0.x);
            a0.z += bflo(u0.y); a0.w += bfhi(u0.y);
            a1.x += bflo(u1.x); a1.y += bfhi(u1.x);
            a1.z += bflo(u1.y); a1.w += bfhi(u1.y);
        }
        if (k < k1) {
            const int s0 = srcSorted[k];
            const uint2 u0 = *(const uint2*)(T + (size_t)s0 * HID + j0);
            a0.x += bflo(u0.x); a0.y += bfhi(u0.x);
            a0.z += bflo(u0.y); a0.w += bfhi(u0.y);
        }
        a0.x += a1.x; a0.y += a1.y; a0.z += a1.z; a0.w += a1.w;
        *(float4*)(H + (size_t)node * HID + j0) = a0;
    }
}

// ---------------------------------------------------------------------------
// Gather-reduce (readout): O[node] = bf + sum over edges(dst==node) of S[src].
// ---------------------------------------------------------------------------
__global__ __launch_bounds__(256) void gather_scalar(
    const float* __restrict__ S, const int* __restrict__ offs,
    const int* __restrict__ srcSorted, const float* __restrict__ bf,
    float* __restrict__ O, int n_nodes)
{
    const int t  = blockIdx.x * blockDim.x + threadIdx.x;
    const int nt = gridDim.x * blockDim.x;
    for (int node = t; node < n_nodes; node += nt) {
        const int k0 = offs[node];
        const int k1 = offs[node + 1];
        float acc = bf[0];
        for (int k = k0; k < k1; ++k) acc += S[srcSorted[k]];
        O[node] = acc;
    }
}

// ---------------------------------------------------------------------------
// Fallback atomic path (used only if workspace is too small for CSR)
// ---------------------------------------------------------------------------
__global__ __launch_bounds__(256) void scatter_vec(
    const ushort_t* __restrict__ T, const int* __restrict__ E,
    const int* __restrict__ flag, float* __restrict__ H,
    int n_edges, int n_nodes)
{
    const bool is64 = (flag[0] != 0);
    const int l32 = threadIdx.x & 31;
    const int j0  = l32 * 4;
    const int grp  = (int)((blockIdx.x * blockDim.x + threadIdx.x) >> 5);
    const int ngrp = (int)((gridDim.x * blockDim.x) >> 5);
    for (int e = grp; e < n_edges; e += ngrp) {
        const int src = load_idx(E, e, is64);
        const int dst = load_idx(E, n_edges + e, is64);
        if ((unsigned)src >= (unsigned)n_nodes || (unsigned)dst >= (unsigned)n_nodes) continue;
        const uint2 u = *(const uint2*)(T + (size_t)src * HID + j0);
        float* hp = H + (size_t)dst * HID + j0;
        unsafeAtomicAdd(hp + 0, bflo(u.x));
        unsafeAtomicAdd(hp + 1, bfhi(u.x));
        unsafeAtomicAdd(hp + 2, bflo(u.y));
        unsafeAtomicAdd(hp + 3, bfhi(u.y));
    }
}

__global__ __launch_bounds__(256) void scatter_scalar(
    const float* __restrict__ S, const int* __restrict__ E,
    const int* __restrict__ flag, float* __restrict__ O,
    int n_edges, int n_nodes)
{
    const bool is64 = (flag[0] != 0);
    const int t  = blockIdx.x * blockDim.x + threadIdx.x;
    const int nt = gridDim.x * blockDim.x;
    for (int e = t; e < n_edges; e += nt) {
        const int src = load_idx(E, e, is64);
        const int dst = load_idx(E, n_edges + e, is64);
        if ((unsigned)src >= (unsigned)n_nodes || (unsigned)dst >= (unsigned)n_nodes) continue;
        unsafeAtomicAdd(O + dst, S[src]);
    }
}

__global__ void init_out(float* __restrict__ O, const float* __restrict__ bf, int n) {
    int i = blockIdx.x * blockDim.x + threadIdx.x;
    if (i < n) O[i] = bf[0];
}

extern "C" void kernel_launch(void* const* d_in, const int* in_sizes, int n_in,
                              void* d_out, int out_size, void* d_ws, size_t ws_size,
                              hipStream_t stream) {
    const float* x  = (const float*)d_in[0];
    const int*   E  = (const int*)d_in[1];
    const float* W1 = (const float*)d_in[2];
    const float* b1 = (const float*)d_in[3];
    const float* W2 = (const float*)d_in[4];
    const float* b2 = (const float*)d_in[5];
    const float* Wf = (const float*)d_in[6];
    const float* bf = (const float*)d_in[7];
    float* out = (float*)d_out;

    const int n  = in_sizes[0] / HID;   // 50000 nodes
    const int ne = in_sizes[1] / 2;     // 800000 edges
    const int nbuck  = (n + 31) / 32;   // 1563 buckets
    const int m      = nbuck * NBLK;    // partition counters
    const int nbscan = (m + 255) / 256; // scan blocks

    const size_t featB = (size_t)n * HID * 4;
    char* ws = (char*)d_ws;
    int*      flag = (int*)ws;
    ushort_t* wt1  = (ushort_t*)(ws + 1024);            // 32 KB
    ushort_t* wt2  = (ushort_t*)(ws + 1024 + 32768);    // 32 KB
    ushort_t* t1   = (ushort_t*)(ws + 1024 + 65536);    // n*128 bf16 (in featB slot)
    float*    h1   = (float*)(ws + 1024 + 65536 + featB);
    char*     p    = ws + 1024 + 65536 + 2 * featB;
    uint_t* pe       = (uint_t*)p;              p += (size_t)ne * 4;
    int*   srcSorted = (int*)p;                 p += (size_t)ne * 4;
    int*   offs      = (int*)p;                 p += (size_t)(n + 1) * 4;
    int*   histT     = (int*)p;                 p += (size_t)m * 4;
    int*   basea     = (int*)p;                 p += (size_t)(m + 1) * 4;
    int*   bsum      = (int*)p;                 p += (size_t)nbscan * 4;
    const size_t needed = (size_t)(p - ws);
    float* s = (float*)(ws + 1024 + 65536);   // t1 dead after aggregation; reuse slot

    const int gemm_grid = (n + 63) / 64;

    detect_idx64<<<1, 64, 0, stream>>>(E, flag);
    prep_w<<<128, 256, 0, stream>>>(W1, W2, wt1, wt2);

    // layer 1 per-node transform (bf16 out) via MFMA
    mlp_mfma<<<gemm_grid, 256, 0, stream>>>(x, wt1, b1, nullptr, t1, nullptr, n, 0);

    if (ws_size >= needed && n <= 65536 && nbuck <= MAXBUCK) {
        // ---- coalesced counting partition + exact per-bucket CSR ----
        part_hist<<<NBLK, PTHREADS, 0, stream>>>(E, flag, histT, ne, n, nbuck);
        scang_blk<<<nbscan, 256, 0, stream>>>(histT, basea, bsum, m);
        scang_top<<<1, 256, 0, stream>>>(bsum, basea + m, nbscan);
        scang_add<<<nbscan, 256, 0, stream>>>(basea, bsum, m);
        part_scatter<<<NBLK, PTHREADS, 0, stream>>>(E, flag, basea, pe, ne, n, nbuck);
        bucket_csr<<<nbuck, 64, 0, stream>>>(pe, basea, offs, srcSorted, n, nbuck);

        // ---- aggregation without atomics ----
        gather_vec<<<2048, 256, 0, stream>>>(t1, offs, srcSorted, h1, n);

        // layer 2 fused with readout: s[m] = relu(h1[m]@W2+b2) . Wf
        mlp_mfma<<<gemm_grid, 256, 0, stream>>>(h1, wt2, b2, Wf, nullptr, s, n, 1);

        gather_scalar<<<1024, 256, 0, stream>>>(s, offs, srcSorted, bf, out, n);
    } else {
        // ---- fallback: atomic scatter path ----
        (void)hipMemsetAsync(h1, 0, featB, stream);
        scatter_vec<<<8192, 256, 0, stream>>>(t1, E, flag, h1, ne, n);
        mlp_mfma<<<gemm_grid, 256, 0, stream>>>(h1, wt2, b2, Wf, nullptr, s, n, 1);
        init_out<<<(n + 255) / 256, 256, 0, stream>>>(out, bf, n);
        scatter_scalar<<<2048, 256, 0, stream>>>(s, E, flag, out, ne, n);
    }
}

// Round 11
// 108.269 us; speedup vs baseline: 1.6092x; 1.1065x over previous
//
#include <hip/hip_runtime.h>

#define HID 128
#define NBLK 64          // partition chunks (blocks in part_hist/part_scatter)
#define PTHREADS 1024    // threads per partition block
#define MAXBUCK 2048     // buckets of 32 dst nodes; supports n <= 65536

typedef unsigned short ushort_t;
typedef unsigned int uint_t;
typedef short bf16x8 __attribute__((ext_vector_type(8)));
typedef float f32x4 __attribute__((ext_vector_type(4)));

__device__ __forceinline__ float bflo(uint_t u) { return __uint_as_float(u << 16); }
__device__ __forceinline__ float bfhi(uint_t u) { return __uint_as_float(u & 0xFFFF0000u); }
__device__ __forceinline__ uint_t f2bf(float f) {
    uint_t x = __float_as_uint(f);
    return (x + 0x7FFFu + ((x >> 16) & 1u)) >> 16;   // RNE
}

// ---------------------------------------------------------------------------
// Detect whether edge_index was materialized as int64 (odd 32-bit words all 0)
// or int32. Values are node ids in [0, 50000) so the high word of int64 is 0.
// ---------------------------------------------------------------------------
__global__ void detect_idx64(const int* __restrict__ E, int* __restrict__ flag) {
    int l = threadIdx.x;                       // 64 threads
    int v = E[2 * l + 1] | E[2 * (l + 64) + 1];
    unsigned long long b = __ballot(v != 0);
    if (l == 0) flag[0] = (b == 0ull) ? 1 : 0;
}

__device__ __forceinline__ int load_idx(const int* __restrict__ E, int pos, bool is64) {
    return is64 ? E[2 * pos] : E[pos];
}

// ---------------------------------------------------------------------------
// One-time weight prep: Wt[col][k] = bf16(W[k][col]) for W1 and W2.
// ---------------------------------------------------------------------------
__global__ __launch_bounds__(256) void prep_w(
    const float* __restrict__ W1, const float* __restrict__ W2,
    ushort_t* __restrict__ wt1, ushort_t* __restrict__ wt2)
{
    const int id = blockIdx.x * 256 + threadIdx.x;       // 0..32767
    const float* W = (id < 16384) ? W1 : W2;
    ushort_t* O    = (id < 16384) ? wt1 : wt2;
    const int i   = id & 16383;
    const int col = i >> 7;
    const int k   = i & 127;
    O[col * 128 + k] = (ushort_t)f2bf(W[k * 128 + col]);
}

// ---------------------------------------------------------------------------
// MFMA GEMM: T = relu(X @ W + B) using v_mfma_f32_16x16x32_bf16.
// Block = 256 thr = 4 waves; each wave owns 16 rows x 128 cols.
// Wt (transposed bf16 W) staged once into LDS with granule-XOR swizzle.
// No per-K barriers: LDS is read-only after the single stage barrier.
// C/D layout (verified): col=lane&15, row=(lane>>4)*4+reg.
// mode 0: write T rows (bf16). mode 1: fuse dot with Wf, write scalar S.
// ---------------------------------------------------------------------------
__global__ __launch_bounds__(256) void mlp_mfma(
    const float* __restrict__ X, const ushort_t* __restrict__ Wt,
    const float* __restrict__ Bv, const float* __restrict__ Wf,
    ushort_t* __restrict__ T, float* __restrict__ S, int n, int mode)
{
    __shared__ ushort_t Wl[HID * HID];   // 32 KB, swizzled

    {
        const uint4* src = (const uint4*)Wt;
        for (int o = threadIdx.x; o < 2048; o += 256) {
            const uint4 v = src[o];
            const int col = o >> 4;
            const int g   = o & 15;
            const int gs  = g ^ (col & 7);
            *(uint4*)(Wl + col * HID + gs * 8) = v;
        }
    }
    __syncthreads();

    const int l  = threadIdx.x & 63;
    const int wv = threadIdx.x >> 6;
    const int rowbase = blockIdx.x * 64 + wv * 16;
    const int lr = l & 15;               // A-row / B-col / C-col lane index
    const int lg = l >> 4;               // k-group / C-row group

    f32x4 acc[8];
#pragma unroll
    for (int ct = 0; ct < 8; ++ct) acc[ct] = (f32x4){0.f, 0.f, 0.f, 0.f};

    const int arow = rowbase + lr;
    const bool rok = (arow < n);

    for (int kk = 0; kk < 4; ++kk) {
        bf16x8 a;
        if (rok) {
            const float* xp = X + (size_t)arow * HID + kk * 32 + lg * 8;
            const float4 x0 = *(const float4*)xp;
            const float4 x1 = *(const float4*)(xp + 4);
            a[0] = (short)f2bf(x0.x); a[1] = (short)f2bf(x0.y);
            a[2] = (short)f2bf(x0.z); a[3] = (short)f2bf(x0.w);
            a[4] = (short)f2bf(x1.x); a[5] = (short)f2bf(x1.y);
            a[6] = (short)f2bf(x1.z); a[7] = (short)f2bf(x1.w);
        } else {
            a = (bf16x8){0, 0, 0, 0, 0, 0, 0, 0};
        }
#pragma unroll
        for (int ct = 0; ct < 8; ++ct) {
            const int col = ct * 16 + lr;
            const int g   = kk * 4 + lg;
            const int gs  = g ^ (col & 7);
            const bf16x8 b = *(const bf16x8*)(Wl + col * HID + gs * 8);
            acc[ct] = __builtin_amdgcn_mfma_f32_16x16x32_bf16(a, b, acc[ct], 0, 0, 0);
        }
    }

    if (mode == 0) {
#pragma unroll
        for (int ct = 0; ct < 8; ++ct) {
            const float bvc = Bv[ct * 16 + lr];
#pragma unroll
            for (int i = 0; i < 4; ++i) {
                const int r = rowbase + lg * 4 + i;
                if (r < n) {
                    const float v = fmaxf(acc[ct][i] + bvc, 0.f);
                    T[(size_t)r * HID + ct * 16 + lr] = (ushort_t)f2bf(v);
                }
            }
        }
    } else {
        float p0 = 0.f, p1 = 0.f, p2 = 0.f, p3 = 0.f;
#pragma unroll
        for (int ct = 0; ct < 8; ++ct) {
            const float bvc = Bv[ct * 16 + lr];
            const float wfc = Wf[ct * 16 + lr];
            p0 += fmaxf(acc[ct][0] + bvc, 0.f) * wfc;
            p1 += fmaxf(acc[ct][1] + bvc, 0.f) * wfc;
            p2 += fmaxf(acc[ct][2] + bvc, 0.f) * wfc;
            p3 += fmaxf(acc[ct][3] + bvc, 0.f) * wfc;
        }
#pragma unroll
        for (int m = 1; m <= 8; m <<= 1) {
            p0 += __shfl_xor(p0, m);
            p1 += __shfl_xor(p1, m);
            p2 += __shfl_xor(p2, m);
            p3 += __shfl_xor(p3, m);
        }
        if (lr == 0) {
            const int r = rowbase + lg * 4;
            if (r + 0 < n) S[r + 0] = p0;
            if (r + 1 < n) S[r + 1] = p1;
            if (r + 2 < n) S[r + 2] = p2;
            if (r + 3 < n) S[r + 3] = p3;
        }
    }
}

// ---------------------------------------------------------------------------
// Partition stage 1: per-block LDS histogram of dst buckets (32 dsts/bucket).
// ---------------------------------------------------------------------------
__global__ __launch_bounds__(PTHREADS) void part_hist(
    const int* __restrict__ E, const int* __restrict__ flag,
    int* __restrict__ histT, int n_edges, int n_nodes, int nbuck)
{
    __shared__ int h[MAXBUCK];
    for (int i = threadIdx.x; i < nbuck; i += PTHREADS) h[i] = 0;
    __syncthreads();
    const bool is64 = (flag[0] != 0);
    const int chunk = (n_edges + NBLK - 1) / NBLK;
    const int c0 = blockIdx.x * chunk;
    const int c1 = min(c0 + chunk, n_edges);
    for (int e = c0 + (int)threadIdx.x; e < c1; e += PTHREADS) {
        const int dst = load_idx(E, n_edges + e, is64);
        if ((unsigned)dst < (unsigned)n_nodes) atomicAdd(&h[dst >> 5], 1);
    }
    __syncthreads();
    for (int i = threadIdx.x; i < nbuck; i += PTHREADS)
        histT[i * NBLK + blockIdx.x] = h[i];
}

// ---------------------------------------------------------------------------
// Generic hierarchical exclusive scan (3 kernels) over m elements.
// ---------------------------------------------------------------------------
__global__ __launch_bounds__(256) void scang_blk(
    const int* __restrict__ A, int* __restrict__ out,
    int* __restrict__ bsum, int m)
{
    __shared__ int sd[256];
    const int t = threadIdx.x;
    const int i = blockIdx.x * 256 + t;
    const int v = (i < m) ? A[i] : 0;
    sd[t] = v;
    __syncthreads();
    for (int d = 1; d < 256; d <<= 1) {
        const int u = (t >= d) ? sd[t - d] : 0;
        __syncthreads();
        sd[t] += u;
        __syncthreads();
    }
    if (i < m) out[i] = sd[t] - v;           // local exclusive
    if (t == 255) bsum[blockIdx.x] = sd[255];
}

__global__ __launch_bounds__(256) void scang_top(
    int* __restrict__ bsum, int* __restrict__ totalSlot, int nb)
{
    __shared__ int sd[256];
    const int t = threadIdx.x;
    const int chunk = (nb + 255) / 256;
    const int lo = t * chunk;
    const int hi = min(lo + chunk, nb);
    int s = 0;
    for (int i = lo; i < hi; ++i) s += bsum[i];
    sd[t] = s;
    __syncthreads();
    for (int d = 1; d < 256; d <<= 1) {
        const int u = (t >= d) ? sd[t - d] : 0;
        __syncthreads();
        sd[t] += u;
        __syncthreads();
    }
    int run = sd[t] - s;
    for (int i = lo; i < hi; ++i) {
        const int c = bsum[i];
        bsum[i] = run;                        // block base
        run += c;
    }
    if (t == 255) totalSlot[0] = sd[255];
}

__global__ __launch_bounds__(256) void scang_add(
    int* __restrict__ out, const int* __restrict__ bsum, int m)
{
    const int i = blockIdx.x * 256 + threadIdx.x;
    if (i < m) out[i] += bsum[blockIdx.x];
}

// ---------------------------------------------------------------------------
// Partition stage 2: scatter packed (src | dlow<<16) into per-(block,bucket)
// EXCLUSIVE ranges.
// ---------------------------------------------------------------------------
__global__ __launch_bounds__(PTHREADS) void part_scatter(
    const int* __restrict__ E, const int* __restrict__ flag,
    const int* __restrict__ base, uint_t* __restrict__ pe,
    int n_edges, int n_nodes, int nbuck)
{
    __shared__ int cur[MAXBUCK];
    for (int i = threadIdx.x; i < nbuck; i += PTHREADS)
        cur[i] = base[i * NBLK + blockIdx.x];
    __syncthreads();
    const bool is64 = (flag[0] != 0);
    const int chunk = (n_edges + NBLK - 1) / NBLK;
    const int c0 = blockIdx.x * chunk;
    const int c1 = min(c0 + chunk, n_edges);
    for (int e = c0 + (int)threadIdx.x; e < c1; e += PTHREADS) {
        const int src = load_idx(E, e, is64);
        const int dst = load_idx(E, n_edges + e, is64);
        if ((unsigned)src >= (unsigned)n_nodes || (unsigned)dst >= (unsigned)n_nodes) continue;
        const int p = atomicAdd(&cur[dst >> 5], 1);
        pe[p] = (uint_t)src | ((uint_t)(dst & 31) << 16);
    }
}

// ---------------------------------------------------------------------------
// Per-bucket exact CSR: one wave per bucket of 32 dsts.
// ---------------------------------------------------------------------------
__global__ __launch_bounds__(64) void bucket_csr(
    const uint_t* __restrict__ pe, const int* __restrict__ base,
    int* __restrict__ offs, int* __restrict__ srcS,
    int n_nodes, int nbuck)
{
    __shared__ int cnt[32];
    __shared__ int cur[32];
    const int b = blockIdx.x;
    const int l = threadIdx.x;
    const int start = base[b * NBLK];
    const int end   = base[(b + 1) * NBLK];   // base has nbuck*NBLK+1 entries
    if (l < 32) cnt[l] = 0;
    __syncthreads();
    for (int i = start + l; i < end; i += 64)
        atomicAdd(&cnt[(pe[i] >> 16) & 31], 1);
    __syncthreads();
    if (l < 32) {
        const int v = cnt[l];
        int s = v;
        for (int d = 1; d < 32; d <<= 1) {
            const int u = __shfl_up(s, d, 64);
            if (l >= d) s += u;
        }
        const int o = start + s - v;          // exclusive within bucket
        const int dst = b * 32 + l;
        if (dst < n_nodes) offs[dst] = o;
        cur[l] = o;
    }
    __syncthreads();
    for (int i = start + l; i < end; i += 64) {
        const uint_t w = pe[i];
        const int p = atomicAdd(&cur[(w >> 16) & 31], 1);
        srcS[p] = (int)(w & 0xFFFFu);
    }
    if (b == 0 && l == 0) offs[n_nodes] = base[nbuck * NBLK];
}

// ---------------------------------------------------------------------------
// Gather-reduce (layer 1): H[node] = sum over edges(dst==node) of T[src].
// 32 lanes per node. Index batching: one coalesced load grabs up to 32
// edge indices; __shfl broadcasts them so the T-row loads are issued
// 4-at-a-time with no index-load on the critical path (MLP via ILP).
// ---------------------------------------------------------------------------
__global__ __launch_bounds__(256) void gather_vec(
    const ushort_t* __restrict__ T, const int* __restrict__ offs,
    const int* __restrict__ srcSorted, float* __restrict__ H, int n_nodes)
{
    const int l32  = threadIdx.x & 31;
    const int j0   = l32 * 4;
    const int grp  = (int)((blockIdx.x * blockDim.x + threadIdx.x) >> 5);
    const int ngrp = (int)((gridDim.x * blockDim.x) >> 5);
    for (int node = grp; node < n_nodes; node += ngrp) {
        const int k0 = offs[node];
        const int k1 = offs[node + 1];
        float4 a0 = {0.f, 0.f, 0.f, 0.f};
        float4 a1 = {0.f, 0.f, 0.f, 0.f};
        float4 a2 = {0.f, 0.f, 0.f, 0.f};
        float4 a3 = {0.f, 0.f, 0.f, 0.f};
        for (int kb = k0; kb < k1; kb += 32) {
            const int cnt = min(32, k1 - kb);
            const int idx = (l32 < cnt) ? srcSorted[kb + l32] : 0;
            int k = 0;
            for (; k + 4 <= cnt; k += 4) {
                const int s0 = __shfl(idx, k + 0, 32);
                const int s1 = __shfl(idx, k + 1, 32);
                const int s2 = __shfl(idx, k + 2, 32);
                const int s3 = __shfl(idx, k + 3, 32);
                const uint2 u0 = *(const uint2*)(T + (size_t)s0 * HID + j0);
                const uint2 u1 = *(const uint2*)(T + (size_t)s1 * HID + j0);
                const uint2 u2 = *(const uint2*)(T + (size_t)s2 * HID + j0);
                const uint2 u3 = *(const uint2*)(T + (size_t)s3 * HID + j0);
                a0.x += bflo(u0.x); a0.y += bfhi(u0.x);
                a0.z += bflo(u0.y); a0.w += bfhi(u0.y);
                a1.x += bflo(u1.x); a1.y += bfhi(u1.x);
                a1.z += bflo(u1.y); a1.w += bfhi(u1.y);
                a2.x += bflo(u2.x); a2.y += bfhi(u2.x);
                a2.z += bflo(u2.y); a2.w += bfhi(u2.y);
                a3.x += bflo(u3.x); a3.y += bfhi(u3.x);
                a3.z += bflo(u3.y); a3.w += bfhi(u3.y);
            }
            for (; k < cnt; ++k) {
                const int s0 = __shfl(idx, k, 32);
                const uint2 u0 = *(const uint2*)(T + (size_t)s0 * HID + j0);
                a0.x += bflo(u0.x); a0.y += bfhi(u0.x);
                a0.z += bflo(u0.y); a0.w += bfhi(u0.y);
            }
        }
        a0.x += a1.x + a2.x + a3.x;
        a0.y += a1.y + a2.y + a3.y;
        a0.z += a1.z + a2.z + a3.z;
        a0.w += a1.w + a2.w + a3.w;
        *(float4*)(H + (size_t)node * HID + j0) = a0;
    }
}

// ---------------------------------------------------------------------------
// Gather-reduce (readout): O[node] = bf + sum over edges(dst==node) of S[src].
// 4 independent load chains (index loads are sequential -> independent).
// ---------------------------------------------------------------------------
__global__ __launch_bounds__(256) void gather_scalar(
    const float* __restrict__ S, const int* __restrict__ offs,
    const int* __restrict__ srcSorted, const float* __restrict__ bf,
    float* __restrict__ O, int n_nodes)
{
    const int t  = blockIdx.x * blockDim.x + threadIdx.x;
    const int nt = gridDim.x * blockDim.x;
    for (int node = t; node < n_nodes; node += nt) {
        const int k0 = offs[node];
        const int k1 = offs[node + 1];
        float a0 = 0.f, a1 = 0.f, a2 = 0.f, a3 = 0.f;
        int k = k0;
        for (; k + 4 <= k1; k += 4) {
            const int s0 = srcSorted[k + 0];
            const int s1 = srcSorted[k + 1];
            const int s2 = srcSorted[k + 2];
            const int s3 = srcSorted[k + 3];
            a0 += S[s0]; a1 += S[s1]; a2 += S[s2]; a3 += S[s3];
        }
        for (; k < k1; ++k) a0 += S[srcSorted[k]];
        O[node] = bf[0] + a0 + a1 + a2 + a3;
    }
}

// ---------------------------------------------------------------------------
// Fallback atomic path (used only if workspace is too small for CSR)
// ---------------------------------------------------------------------------
__global__ __launch_bounds__(256) void scatter_vec(
    const ushort_t* __restrict__ T, const int* __restrict__ E,
    const int* __restrict__ flag, float* __restrict__ H,
    int n_edges, int n_nodes)
{
    const bool is64 = (flag[0] != 0);
    const int l32 = threadIdx.x & 31;
    const int j0  = l32 * 4;
    const int grp  = (int)((blockIdx.x * blockDim.x + threadIdx.x) >> 5);
    const int ngrp = (int)((gridDim.x * blockDim.x) >> 5);
    for (int e = grp; e < n_edges; e += ngrp) {
        const int src = load_idx(E, e, is64);
        const int dst = load_idx(E, n_edges + e, is64);
        if ((unsigned)src >= (unsigned)n_nodes || (unsigned)dst >= (unsigned)n_nodes) continue;
        const uint2 u = *(const uint2*)(T + (size_t)src * HID + j0);
        float* hp = H + (size_t)dst * HID + j0;
        unsafeAtomicAdd(hp + 0, bflo(u.x));
        unsafeAtomicAdd(hp + 1, bfhi(u.x));
        unsafeAtomicAdd(hp + 2, bflo(u.y));
        unsafeAtomicAdd(hp + 3, bfhi(u.y));
    }
}

__global__ __launch_bounds__(256) void scatter_scalar(
    const float* __restrict__ S, const int* __restrict__ E,
    const int* __restrict__ flag, float* __restrict__ O,
    int n_edges, int n_nodes)
{
    const bool is64 = (flag[0] != 0);
    const int t  = blockIdx.x * blockDim.x + threadIdx.x;
    const int nt = gridDim.x * blockDim.x;
    for (int e = t; e < n_edges; e += nt) {
        const int src = load_idx(E, e, is64);
        const int dst = load_idx(E, n_edges + e, is64);
        if ((unsigned)src >= (unsigned)n_nodes || (unsigned)dst >= (unsigned)n_nodes) continue;
        unsafeAtomicAdd(O + dst, S[src]);
    }
}

__global__ void init_out(float* __restrict__ O, const float* __restrict__ bf, int n) {
    int i = blockIdx.x * blockDim.x + threadIdx.x;
    if (i < n) O[i] = bf[0];
}

extern "C" void kernel_launch(void* const* d_in, const int* in_sizes, int n_in,
                              void* d_out, int out_size, void* d_ws, size_t ws_size,
                              hipStream_t stream) {
    const float* x  = (const float*)d_in[0];
    const int*   E  = (const int*)d_in[1];
    const float* W1 = (const float*)d_in[2];
    const float* b1 = (const float*)d_in[3];
    const float* W2 = (const float*)d_in[4];
    const float* b2 = (const float*)d_in[5];
    const float* Wf = (const float*)d_in[6];
    const float* bf = (const float*)d_in[7];
    float* out = (float*)d_out;

    const int n  = in_sizes[0] / HID;   // 50000 nodes
    const int ne = in_sizes[1] / 2;     // 800000 edges
    const int nbuck  = (n + 31) / 32;   // 1563 buckets
    const int m      = nbuck * NBLK;    // partition counters
    const int nbscan = (m + 255) / 256; // scan blocks

    const size_t featB = (size_t)n * HID * 4;
    char* ws = (char*)d_ws;
    int*      flag = (int*)ws;
    ushort_t* wt1  = (ushort_t*)(ws + 1024);            // 32 KB
    ushort_t* wt2  = (ushort_t*)(ws + 1024 + 32768);    // 32 KB
    ushort_t* t1   = (ushort_t*)(ws + 1024 + 65536);    // n*128 bf16 (in featB slot)
    float*    h1   = (float*)(ws + 1024 + 65536 + featB);
    char*     p    = ws + 1024 + 65536 + 2 * featB;
    uint_t* pe       = (uint_t*)p;              p += (size_t)ne * 4;
    int*   srcSorted = (int*)p;                 p += (size_t)ne * 4;
    int*   offs      = (int*)p;                 p += (size_t)(n + 1) * 4;
    int*   histT     = (int*)p;                 p += (size_t)m * 4;
    int*   basea     = (int*)p;                 p += (size_t)(m + 1) * 4;
    int*   bsum      = (int*)p;                 p += (size_t)nbscan * 4;
    const size_t needed = (size_t)(p - ws);
    float* s = (float*)(ws + 1024 + 65536);   // t1 dead after aggregation; reuse slot

    const int gemm_grid = (n + 63) / 64;

    detect_idx64<<<1, 64, 0, stream>>>(E, flag);
    prep_w<<<128, 256, 0, stream>>>(W1, W2, wt1, wt2);

    // layer 1 per-node transform (bf16 out) via MFMA
    mlp_mfma<<<gemm_grid, 256, 0, stream>>>(x, wt1, b1, nullptr, t1, nullptr, n, 0);

    if (ws_size >= needed && n <= 65536 && nbuck <= MAXBUCK) {
        // ---- coalesced counting partition + exact per-bucket CSR ----
        part_hist<<<NBLK, PTHREADS, 0, stream>>>(E, flag, histT, ne, n, nbuck);
        scang_blk<<<nbscan, 256, 0, stream>>>(histT, basea, bsum, m);
        scang_top<<<1, 256, 0, stream>>>(bsum, basea + m, nbscan);
        scang_add<<<nbscan, 256, 0, stream>>>(basea, bsum, m);
        part_scatter<<<NBLK, PTHREADS, 0, stream>>>(E, flag, basea, pe, ne, n, nbuck);
        bucket_csr<<<nbuck, 64, 0, stream>>>(pe, basea, offs, srcSorted, n, nbuck);

        // ---- aggregation without atomics ----
        gather_vec<<<2048, 256, 0, stream>>>(t1, offs, srcSorted, h1, n);

        // layer 2 fused with readout: s[m] = relu(h1[m]@W2+b2) . Wf
        mlp_mfma<<<gemm_grid, 256, 0, stream>>>(h1, wt2, b2, Wf, nullptr, s, n, 1);

        gather_scalar<<<1024, 256, 0, stream>>>(s, offs, srcSorted, bf, out, n);
    } else {
        // ---- fallback: atomic scatter path ----
        (void)hipMemsetAsync(h1, 0, featB, stream);
        scatter_vec<<<8192, 256, 0, stream>>>(t1, E, flag, h1, ne, n);
        mlp_mfma<<<gemm_grid, 256, 0, stream>>>(h1, wt2, b2, Wf, nullptr, s, n, 1);
        init_out<<<(n + 255) / 256, 256, 0, stream>>>(out, bf, n);
        scatter_scalar<<<2048, 256, 0, stream>>>(s, E, flag, out, ne, n);
    }
}

// Round 12
// 103.276 us; speedup vs baseline: 1.6870x; 1.0483x over previous
//
#include <hip/hip_runtime.h>

#define HID 128
#define NBLK 64          // partition chunks (blocks in part_hist/part_scatter)
#define PTHREADS 1024    // threads per partition block
#define MAXBUCK 2048     // buckets of 32 dst nodes; supports n <= 65536
#define CAP 3072         // LDS capacity (edges) per bucket in bucket_gather

typedef unsigned short ushort_t;
typedef unsigned int uint_t;
typedef short bf16x8 __attribute__((ext_vector_type(8)));
typedef float f32x4 __attribute__((ext_vector_type(4)));

__device__ __forceinline__ float bflo(uint_t u) { return __uint_as_float(u << 16); }
__device__ __forceinline__ float bfhi(uint_t u) { return __uint_as_float(u & 0xFFFF0000u); }
__device__ __forceinline__ uint_t f2bf(float f) {
    uint_t x = __float_as_uint(f);
    return (x + 0x7FFFu + ((x >> 16) & 1u)) >> 16;   // RNE
}

__device__ __forceinline__ int load_idx(const int* __restrict__ E, int pos, bool is64) {
    return is64 ? E[2 * pos] : E[pos];
}

// ---------------------------------------------------------------------------
// prep_all: blocks 0..127 transpose W1/W2 to bf16 Wt[col][k]; block 128
// detects int64 vs int32 edge_index layout (odd 32-bit words all zero).
// ---------------------------------------------------------------------------
__global__ __launch_bounds__(256) void prep_all(
    const int* __restrict__ E, int* __restrict__ flag,
    const float* __restrict__ W1, const float* __restrict__ W2,
    ushort_t* __restrict__ wt1, ushort_t* __restrict__ wt2)
{
    if (blockIdx.x == 128) {
        if (threadIdx.x < 64) {
            const int l = threadIdx.x;
            const int v = E[2 * l + 1] | E[2 * (l + 64) + 1];
            unsigned long long b = __ballot(v != 0);
            if (l == 0) flag[0] = (b == 0ull) ? 1 : 0;
        }
        return;
    }
    const int id = blockIdx.x * 256 + threadIdx.x;       // 0..32767
    const float* W = (id < 16384) ? W1 : W2;
    ushort_t* O    = (id < 16384) ? wt1 : wt2;
    const int i   = id & 16383;
    const int col = i >> 7;
    const int k   = i & 127;
    O[col * 128 + k] = (ushort_t)f2bf(W[k * 128 + col]);
}

// ---------------------------------------------------------------------------
// MFMA GEMM: T = relu(X @ W + B) using v_mfma_f32_16x16x32_bf16.
// Block = 256 thr = 4 waves; each wave owns 16 rows x 128 cols.
// Wt (transposed bf16 W) staged once into LDS with granule-XOR swizzle.
// No per-K barriers: LDS is read-only after the single stage barrier.
// C/D layout (verified): col=lane&15, row=(lane>>4)*4+reg.
// mode 0: write T rows (bf16). mode 1: fuse dot with Wf, write scalar S.
// ---------------------------------------------------------------------------
__global__ __launch_bounds__(256) void mlp_mfma(
    const float* __restrict__ X, const ushort_t* __restrict__ Wt,
    const float* __restrict__ Bv, const float* __restrict__ Wf,
    ushort_t* __restrict__ T, float* __restrict__ S, int n, int mode)
{
    __shared__ ushort_t Wl[HID * HID];   // 32 KB, swizzled

    {
        const uint4* src = (const uint4*)Wt;
        for (int o = threadIdx.x; o < 2048; o += 256) {
            const uint4 v = src[o];
            const int col = o >> 4;
            const int g   = o & 15;
            const int gs  = g ^ (col & 7);
            *(uint4*)(Wl + col * HID + gs * 8) = v;
        }
    }
    __syncthreads();

    const int l  = threadIdx.x & 63;
    const int wv = threadIdx.x >> 6;
    const int rowbase = blockIdx.x * 64 + wv * 16;
    const int lr = l & 15;               // A-row / B-col / C-col lane index
    const int lg = l >> 4;               // k-group / C-row group

    f32x4 acc[8];
#pragma unroll
    for (int ct = 0; ct < 8; ++ct) acc[ct] = (f32x4){0.f, 0.f, 0.f, 0.f};

    const int arow = rowbase + lr;
    const bool rok = (arow < n);

    for (int kk = 0; kk < 4; ++kk) {
        bf16x8 a;
        if (rok) {
            const float* xp = X + (size_t)arow * HID + kk * 32 + lg * 8;
            const float4 x0 = *(const float4*)xp;
            const float4 x1 = *(const float4*)(xp + 4);
            a[0] = (short)f2bf(x0.x); a[1] = (short)f2bf(x0.y);
            a[2] = (short)f2bf(x0.z); a[3] = (short)f2bf(x0.w);
            a[4] = (short)f2bf(x1.x); a[5] = (short)f2bf(x1.y);
            a[6] = (short)f2bf(x1.z); a[7] = (short)f2bf(x1.w);
        } else {
            a = (bf16x8){0, 0, 0, 0, 0, 0, 0, 0};
        }
#pragma unroll
        for (int ct = 0; ct < 8; ++ct) {
            const int col = ct * 16 + lr;
            const int g   = kk * 4 + lg;
            const int gs  = g ^ (col & 7);
            const bf16x8 b = *(const bf16x8*)(Wl + col * HID + gs * 8);
            acc[ct] = __builtin_amdgcn_mfma_f32_16x16x32_bf16(a, b, acc[ct], 0, 0, 0);
        }
    }

    if (mode == 0) {
#pragma unroll
        for (int ct = 0; ct < 8; ++ct) {
            const float bvc = Bv[ct * 16 + lr];
#pragma unroll
            for (int i = 0; i < 4; ++i) {
                const int r = rowbase + lg * 4 + i;
                if (r < n) {
                    const float v = fmaxf(acc[ct][i] + bvc, 0.f);
                    T[(size_t)r * HID + ct * 16 + lr] = (ushort_t)f2bf(v);
                }
            }
        }
    } else {
        float p0 = 0.f, p1 = 0.f, p2 = 0.f, p3 = 0.f;
#pragma unroll
        for (int ct = 0; ct < 8; ++ct) {
            const float bvc = Bv[ct * 16 + lr];
            const float wfc = Wf[ct * 16 + lr];
            p0 += fmaxf(acc[ct][0] + bvc, 0.f) * wfc;
            p1 += fmaxf(acc[ct][1] + bvc, 0.f) * wfc;
            p2 += fmaxf(acc[ct][2] + bvc, 0.f) * wfc;
            p3 += fmaxf(acc[ct][3] + bvc, 0.f) * wfc;
        }
#pragma unroll
        for (int m = 1; m <= 8; m <<= 1) {
            p0 += __shfl_xor(p0, m);
            p1 += __shfl_xor(p1, m);
            p2 += __shfl_xor(p2, m);
            p3 += __shfl_xor(p3, m);
        }
        if (lr == 0) {
            const int r = rowbase + lg * 4;
            if (r + 0 < n) S[r + 0] = p0;
            if (r + 1 < n) S[r + 1] = p1;
            if (r + 2 < n) S[r + 2] = p2;
            if (r + 3 < n) S[r + 3] = p3;
        }
    }
}

// ---------------------------------------------------------------------------
// Partition stage 1: per-block LDS histogram of dst buckets (32 dsts/bucket).
// ---------------------------------------------------------------------------
__global__ __launch_bounds__(PTHREADS) void part_hist(
    const int* __restrict__ E, const int* __restrict__ flag,
    int* __restrict__ histT, int n_edges, int n_nodes, int nbuck)
{
    __shared__ int h[MAXBUCK];
    for (int i = threadIdx.x; i < nbuck; i += PTHREADS) h[i] = 0;
    __syncthreads();
    const bool is64 = (flag[0] != 0);
    const int chunk = (n_edges + NBLK - 1) / NBLK;
    const int c0 = blockIdx.x * chunk;
    const int c1 = min(c0 + chunk, n_edges);
    for (int e = c0 + (int)threadIdx.x; e < c1; e += PTHREADS) {
        const int dst = load_idx(E, n_edges + e, is64);
        if ((unsigned)dst < (unsigned)n_nodes) atomicAdd(&h[dst >> 5], 1);
    }
    __syncthreads();
    for (int i = threadIdx.x; i < nbuck; i += PTHREADS)
        histT[i * NBLK + blockIdx.x] = h[i];
}

// ---------------------------------------------------------------------------
// Generic hierarchical exclusive scan (3 kernels) over m elements.
// ---------------------------------------------------------------------------
__global__ __launch_bounds__(256) void scang_blk(
    const int* __restrict__ A, int* __restrict__ out,
    int* __restrict__ bsum, int m)
{
    __shared__ int sd[256];
    const int t = threadIdx.x;
    const int i = blockIdx.x * 256 + t;
    const int v = (i < m) ? A[i] : 0;
    sd[t] = v;
    __syncthreads();
    for (int d = 1; d < 256; d <<= 1) {
        const int u = (t >= d) ? sd[t - d] : 0;
        __syncthreads();
        sd[t] += u;
        __syncthreads();
    }
    if (i < m) out[i] = sd[t] - v;           // local exclusive
    if (t == 255) bsum[blockIdx.x] = sd[255];
}

__global__ __launch_bounds__(256) void scang_top(
    int* __restrict__ bsum, int* __restrict__ totalSlot, int nb)
{
    __shared__ int sd[256];
    const int t = threadIdx.x;
    const int chunk = (nb + 255) / 256;
    const int lo = t * chunk;
    const int hi = min(lo + chunk, nb);
    int s = 0;
    for (int i = lo; i < hi; ++i) s += bsum[i];
    sd[t] = s;
    __syncthreads();
    for (int d = 1; d < 256; d <<= 1) {
        const int u = (t >= d) ? sd[t - d] : 0;
        __syncthreads();
        sd[t] += u;
        __syncthreads();
    }
    int run = sd[t] - s;
    for (int i = lo; i < hi; ++i) {
        const int c = bsum[i];
        bsum[i] = run;                        // block base
        run += c;
    }
    if (t == 255) totalSlot[0] = sd[255];
}

__global__ __launch_bounds__(256) void scang_add(
    int* __restrict__ out, const int* __restrict__ bsum, int m)
{
    const int i = blockIdx.x * 256 + threadIdx.x;
    if (i < m) out[i] += bsum[blockIdx.x];
}

// ---------------------------------------------------------------------------
// Partition stage 2: scatter packed (src | dlow<<16) into per-(block,bucket)
// EXCLUSIVE ranges.
// ---------------------------------------------------------------------------
__global__ __launch_bounds__(PTHREADS) void part_scatter(
    const int* __restrict__ E, const int* __restrict__ flag,
    const int* __restrict__ base, uint_t* __restrict__ pe,
    int n_edges, int n_nodes, int nbuck)
{
    __shared__ int cur[MAXBUCK];
    for (int i = threadIdx.x; i < nbuck; i += PTHREADS)
        cur[i] = base[i * NBLK + blockIdx.x];
    __syncthreads();
    const bool is64 = (flag[0] != 0);
    const int chunk = (n_edges + NBLK - 1) / NBLK;
    const int c0 = blockIdx.x * chunk;
    const int c1 = min(c0 + chunk, n_edges);
    for (int e = c0 + (int)threadIdx.x; e < c1; e += PTHREADS) {
        const int src = load_idx(E, e, is64);
        const int dst = load_idx(E, n_edges + e, is64);
        if ((unsigned)src >= (unsigned)n_nodes || (unsigned)dst >= (unsigned)n_nodes) continue;
        const int p = atomicAdd(&cur[dst >> 5], 1);
        pe[p] = (uint_t)src | ((uint_t)(dst & 31) << 16);
    }
}

// ---------------------------------------------------------------------------
// Fused bucket CSR + vector gather: one 256-thread block per bucket of 32
// dst nodes. Builds the per-dst sorted src list in LDS (count -> shfl-scan
// -> place), writes offs/srcS to global (for the later scalar pass), then
// 8 x 32-lane groups gather T rows using LDS-resident indices and write H.
// No global index round-trip, no separate bucket_csr kernel.
// ---------------------------------------------------------------------------
__global__ __launch_bounds__(256) void bucket_gather(
    const uint_t* __restrict__ pe, const int* __restrict__ base,
    const ushort_t* __restrict__ T, float* __restrict__ H,
    int* __restrict__ offs, int* __restrict__ srcS,
    int n_nodes, int nbuck)
{
    __shared__ int sid[CAP];
    __shared__ int cnt[32];
    __shared__ int cur[32];
    __shared__ int loff[32];
    const int b = blockIdx.x;
    const int t = threadIdx.x;
    const int start = base[b * NBLK];
    const int end   = base[(b + 1) * NBLK];
    const int m     = end - start;

    if (t < 32) cnt[t] = 0;
    __syncthreads();
    for (int i = start + t; i < end; i += 256)
        atomicAdd(&cnt[(pe[i] >> 16) & 31], 1);
    __syncthreads();
    if (t < 32) {
        const int v = cnt[t];
        int s = v;
        for (int d = 1; d < 32; d <<= 1) {
            const int u = __shfl_up(s, d, 64);
            if (t >= d) s += u;
        }
        const int excl = s - v;
        loff[t] = excl;
        cur[t]  = excl;
        const int dst = b * 32 + t;
        if (dst <= n_nodes) offs[dst] = start + excl;
    }
    if (b == 0 && t == 0) offs[n_nodes] = base[nbuck * NBLK];
    __syncthreads();

    const bool fits = (m <= CAP);
    for (int i = start + t; i < end; i += 256) {
        const uint_t w = pe[i];
        const int p = atomicAdd(&cur[(w >> 16) & 31], 1);
        const int s = (int)(w & 0xFFFFu);
        if (fits) sid[p] = s;
        else      srcS[start + p] = s;
    }
    __syncthreads();
    if (fits) {
        for (int i = t; i < m; i += 256) srcS[start + i] = sid[i];   // for scalar pass
    }

    const int grp = t >> 5;
    const int l32 = t & 31;
    const int j0  = l32 * 4;
    for (int nd = grp; nd < 32; nd += 8) {
        const int node = b * 32 + nd;
        if (node >= n_nodes) break;
        const int k0 = loff[nd];
        const int k1 = (nd < 31) ? loff[nd + 1] : m;
        float4 a0 = {0.f, 0.f, 0.f, 0.f};
        float4 a1 = {0.f, 0.f, 0.f, 0.f};
        float4 a2 = {0.f, 0.f, 0.f, 0.f};
        float4 a3 = {0.f, 0.f, 0.f, 0.f};
        int k = k0;
        for (; k + 4 <= k1; k += 4) {
            const int s0 = fits ? sid[k + 0] : srcS[start + k + 0];
            const int s1 = fits ? sid[k + 1] : srcS[start + k + 1];
            const int s2 = fits ? sid[k + 2] : srcS[start + k + 2];
            const int s3 = fits ? sid[k + 3] : srcS[start + k + 3];
            const uint2 u0 = *(const uint2*)(T + (size_t)s0 * HID + j0);
            const uint2 u1 = *(const uint2*)(T + (size_t)s1 * HID + j0);
            const uint2 u2 = *(const uint2*)(T + (size_t)s2 * HID + j0);
            const uint2 u3 = *(const uint2*)(T + (size_t)s3 * HID + j0);
            a0.x += bflo(u0.x); a0.y += bfhi(u0.x);
            a0.z += bflo(u0.y); a0.w += bfhi(u0.y);
            a1.x += bflo(u1.x); a1.y += bfhi(u1.x);
            a1.z += bflo(u1.y); a1.w += bfhi(u1.y);
            a2.x += bflo(u2.x); a2.y += bfhi(u2.x);
            a2.z += bflo(u2.y); a2.w += bfhi(u2.y);
            a3.x += bflo(u3.x); a3.y += bfhi(u3.x);
            a3.z += bflo(u3.y); a3.w += bfhi(u3.y);
        }
        for (; k < k1; ++k) {
            const int s0 = fits ? sid[k] : srcS[start + k];
            const uint2 u0 = *(const uint2*)(T + (size_t)s0 * HID + j0);
            a0.x += bflo(u0.x); a0.y += bfhi(u0.x);
            a0.z += bflo(u0.y); a0.w += bfhi(u0.y);
        }
        a0.x += a1.x + a2.x + a3.x;
        a0.y += a1.y + a2.y + a3.y;
        a0.z += a1.z + a2.z + a3.z;
        a0.w += a1.w + a2.w + a3.w;
        *(float4*)(H + (size_t)node * HID + j0) = a0;
    }
}

// ---------------------------------------------------------------------------
// Gather-reduce (readout): O[node] = bf + sum over edges(dst==node) of S[src].
// 4 independent load chains.
// ---------------------------------------------------------------------------
__global__ __launch_bounds__(256) void gather_scalar(
    const float* __restrict__ S, const int* __restrict__ offs,
    const int* __restrict__ srcSorted, const float* __restrict__ bf,
    float* __restrict__ O, int n_nodes)
{
    const int t  = blockIdx.x * blockDim.x + threadIdx.x;
    const int nt = gridDim.x * blockDim.x;
    for (int node = t; node < n_nodes; node += nt) {
        const int k0 = offs[node];
        const int k1 = offs[node + 1];
        float a0 = 0.f, a1 = 0.f, a2 = 0.f, a3 = 0.f;
        int k = k0;
        for (; k + 4 <= k1; k += 4) {
            const int s0 = srcSorted[k + 0];
            const int s1 = srcSorted[k + 1];
            const int s2 = srcSorted[k + 2];
            const int s3 = srcSorted[k + 3];
            a0 += S[s0]; a1 += S[s1]; a2 += S[s2]; a3 += S[s3];
        }
        for (; k < k1; ++k) a0 += S[srcSorted[k]];
        O[node] = bf[0] + a0 + a1 + a2 + a3;
    }
}

// ---------------------------------------------------------------------------
// Fallback atomic path (used only if workspace is too small for CSR)
// ---------------------------------------------------------------------------
__global__ __launch_bounds__(256) void scatter_vec(
    const ushort_t* __restrict__ T, const int* __restrict__ E,
    const int* __restrict__ flag, float* __restrict__ H,
    int n_edges, int n_nodes)
{
    const bool is64 = (flag[0] != 0);
    const int l32 = threadIdx.x & 31;
    const int j0  = l32 * 4;
    const int grp  = (int)((blockIdx.x * blockDim.x + threadIdx.x) >> 5);
    const int ngrp = (int)((gridDim.x * blockDim.x) >> 5);
    for (int e = grp; e < n_edges; e += ngrp) {
        const int src = load_idx(E, e, is64);
        const int dst = load_idx(E, n_edges + e, is64);
        if ((unsigned)src >= (unsigned)n_nodes || (unsigned)dst >= (unsigned)n_nodes) continue;
        const uint2 u = *(const uint2*)(T + (size_t)src * HID + j0);
        float* hp = H + (size_t)dst * HID + j0;
        unsafeAtomicAdd(hp + 0, bflo(u.x));
        unsafeAtomicAdd(hp + 1, bfhi(u.x));
        unsafeAtomicAdd(hp + 2, bflo(u.y));
        unsafeAtomicAdd(hp + 3, bfhi(u.y));
    }
}

__global__ __launch_bounds__(256) void scatter_scalar(
    const float* __restrict__ S, const int* __restrict__ E,
    const int* __restrict__ flag, float* __restrict__ O,
    int n_edges, int n_nodes)
{
    const bool is64 = (flag[0] != 0);
    const int t  = blockIdx.x * blockDim.x + threadIdx.x;
    const int nt = gridDim.x * blockDim.x;
    for (int e = t; e < n_edges; e += nt) {
        const int src = load_idx(E, e, is64);
        const int dst = load_idx(E, n_edges + e, is64);
        if ((unsigned)src >= (unsigned)n_nodes || (unsigned)dst >= (unsigned)n_nodes) continue;
        unsafeAtomicAdd(O + dst, S[src]);
    }
}

__global__ void init_out(float* __restrict__ O, const float* __restrict__ bf, int n) {
    int i = blockIdx.x * blockDim.x + threadIdx.x;
    if (i < n) O[i] = bf[0];
}

extern "C" void kernel_launch(void* const* d_in, const int* in_sizes, int n_in,
                              void* d_out, int out_size, void* d_ws, size_t ws_size,
                              hipStream_t stream) {
    const float* x  = (const float*)d_in[0];
    const int*   E  = (const int*)d_in[1];
    const float* W1 = (const float*)d_in[2];
    const float* b1 = (const float*)d_in[3];
    const float* W2 = (const float*)d_in[4];
    const float* b2 = (const float*)d_in[5];
    const float* Wf = (const float*)d_in[6];
    const float* bf = (const float*)d_in[7];
    float* out = (float*)d_out;

    const int n  = in_sizes[0] / HID;   // 50000 nodes
    const int ne = in_sizes[1] / 2;     // 800000 edges
    const int nbuck  = (n + 31) / 32;   // 1563 buckets
    const int m      = nbuck * NBLK;    // partition counters
    const int nbscan = (m + 255) / 256; // scan blocks

    const size_t featB = (size_t)n * HID * 4;
    char* ws = (char*)d_ws;
    int*      flag = (int*)ws;
    ushort_t* wt1  = (ushort_t*)(ws + 1024);            // 32 KB
    ushort_t* wt2  = (ushort_t*)(ws + 1024 + 32768);    // 32 KB
    ushort_t* t1   = (ushort_t*)(ws + 1024 + 65536);    // n*128 bf16 (in featB slot)
    float*    h1   = (float*)(ws + 1024 + 65536 + featB);
    char*     p    = ws + 1024 + 65536 + 2 * featB;
    uint_t* pe       = (uint_t*)p;              p += (size_t)ne * 4;
    int*   srcSorted = (int*)p;                 p += (size_t)ne * 4;
    int*   offs      = (int*)p;                 p += (size_t)(n + 1) * 4;
    int*   histT     = (int*)p;                 p += (size_t)m * 4;
    int*   basea     = (int*)p;                 p += (size_t)(m + 1) * 4;
    int*   bsum      = (int*)p;                 p += (size_t)nbscan * 4;
    const size_t needed = (size_t)(p - ws);
    float* s = (float*)(ws + 1024 + 65536);   // t1 dead after aggregation; reuse slot

    const int gemm_grid = (n + 63) / 64;

    prep_all<<<129, 256, 0, stream>>>(E, flag, W1, W2, wt1, wt2);

    // layer 1 per-node transform (bf16 out) via MFMA
    mlp_mfma<<<gemm_grid, 256, 0, stream>>>(x, wt1, b1, nullptr, t1, nullptr, n, 0);

    if (ws_size >= needed && n <= 65536 && nbuck <= MAXBUCK) {
        // ---- coalesced counting partition ----
        part_hist<<<NBLK, PTHREADS, 0, stream>>>(E, flag, histT, ne, n, nbuck);
        scang_blk<<<nbscan, 256, 0, stream>>>(histT, basea, bsum, m);
        scang_top<<<1, 256, 0, stream>>>(bsum, basea + m, nbscan);
        scang_add<<<nbscan, 256, 0, stream>>>(basea, bsum, m);
        part_scatter<<<NBLK, PTHREADS, 0, stream>>>(E, flag, basea, pe, ne, n, nbuck);

        // ---- fused bucket CSR + vector gather (writes H, offs, srcS) ----
        bucket_gather<<<nbuck, 256, 0, stream>>>(pe, basea, t1, h1, offs, srcSorted, n, nbuck);

        // layer 2 fused with readout: s[m] = relu(h1[m]@W2+b2) . Wf
        mlp_mfma<<<gemm_grid, 256, 0, stream>>>(h1, wt2, b2, Wf, nullptr, s, n, 1);

        gather_scalar<<<1024, 256, 0, stream>>>(s, offs, srcSorted, bf, out, n);
    } else {
        // ---- fallback: atomic scatter path ----
        (void)hipMemsetAsync(h1, 0, featB, stream);
        scatter_vec<<<8192, 256, 0, stream>>>(t1, E, flag, h1, ne, n);
        mlp_mfma<<<gemm_grid, 256, 0, stream>>>(h1, wt2, b2, Wf, nullptr, s, n, 1);
        init_out<<<(n + 255) / 256, 256, 0, stream>>>(out, bf, n);
        scatter_scalar<<<2048, 256, 0, stream>>>(s, E, flag, out, ne, n);
    }
}